// Round 3
// baseline (359.866 us; speedup 1.0000x reference)
//
#include <hip/hip_runtime.h>

#define NV 8192
#define NH 4096
#define TPB 256
#define HPB 16                     // h rows per block
#define HCH (NH / HPB)             // 256 h-chunks (gridDim.y)
#define ROW4 (NV / 4)              // 2048 float4 per row
#define VBLK (ROW4 / TPB)          // 8 blocks in x
#define NPART (VBLK * HCH)         // 2048 trace partials (8 KB workspace)
#define CH 4                       // rows per pipeline chunk
#define NCHUNK (HPB / CH)          // 4 chunks, double-buffered in registers

typedef float f32x4 __attribute__((ext_vector_type(4)));  // native vec for nontemporal store

// output layout (flat float offsets, reference return order)
#define OFF_B   ((size_t)0)
#define OFF_WT  ((size_t)NV)
#define OFF_SIG ((size_t)NV + (size_t)NH * (size_t)NV)
#define OFF_MUH (OFF_SIG + 1)
#define OFF_VHD (OFF_MUH + NH)

__global__ __launch_bounds__(TPB) void init_k(
    const float* __restrict__ muvTE,
    const float* __restrict__ varh_diagTE,
    const float* __restrict__ muhTE,
    float* __restrict__ out)
{
    int i = blockIdx.x * TPB + threadIdx.x;     // grid covers NV
    if (i < NV) out[OFF_B + i] = muvTE[i];
    if (i < NH) {
        out[OFF_MUH + i] = muhTE[i];
        out[OFF_VHD + i] = varh_diagTE[i];
    }
}

// __launch_bounds__(256, 4): 128-VGPR budget so the register double-buffer
// (2 bufs x 4 rows x 2 streams x float4 = 64 data VGPRs) stays in registers.
// 4 waves/EU = 16 waves/CU — round 2 proved occupancy above this adds nothing.
__global__ __launch_bounds__(TPB, 4) void main_k(
    const float4* __restrict__ varvhTE4,
    const float4* __restrict__ varvh4,
    const float* __restrict__ varh_diagTE,
    const float* __restrict__ varh_diag,
    const float* __restrict__ muh,
    const float* __restrict__ muhTE,
    float* __restrict__ out,
    float* __restrict__ tr_partial)
{
    __shared__ float4 coef_s[HPB];
    const int t  = threadIdx.x;
    const int h0 = blockIdx.y * HPB;

    // per-h coefficients: {inv, inv*muh, d*muh - inv*muhTE, d}
    if (t < HPB) {
        int h = h0 + t;
        float inv  = 1.0f / varh_diag[h];
        float vte  = varh_diagTE[h];
        float d    = inv * vte * inv;
        float m    = muh[h];
        coef_s[t] = make_float4(inv, inv * m, d * m - inv * muhTE[h], d);
    }
    __syncthreads();

    const int v4 = blockIdx.x * TPB + t;        // float4 column index
    f32x4* wt4 = (f32x4*)(out + OFF_WT);
    const size_t base = (size_t)h0 * ROW4 + (size_t)v4;

    float bx = 0.f, by = 0.f, bz = 0.f, bw = 0.f;
    float tr = 0.f;

    // Software pipeline: issue chunk c+1's 8 loads BEFORE chunk c's
    // compute+stores. All loads of a chunk live in distinct registers, so
    // the wait before compute is a counted vmcnt (younger stores stay
    // outstanding) instead of vmcnt(0) draining the nt-store queue.
    float4 aTE_b[2][CH], a_b[2][CH];

    #pragma unroll
    for (int r = 0; r < CH; ++r) {              // prologue: chunk 0 loads
        size_t idx = base + (size_t)r * ROW4;
        aTE_b[0][r] = varvhTE4[idx];
        a_b[0][r]   = varvh4[idx];
    }

    #pragma unroll
    for (int c = 0; c < NCHUNK; ++c) {          // fully unrolled: static buf indices
        const int cur = c & 1, nxt = cur ^ 1;

        if (c + 1 < NCHUNK) {                   // prefetch next chunk
            #pragma unroll
            for (int r = 0; r < CH; ++r) {
                size_t idx = base + (size_t)((c + 1) * CH + r) * ROW4;
                aTE_b[nxt][r] = varvhTE4[idx];
                a_b[nxt][r]   = varvh4[idx];
            }
        }

        #pragma unroll
        for (int r = 0; r < CH; ++r) {          // compute + store current chunk
            float4 cf  = coef_s[c * CH + r];
            float4 aTE = aTE_b[cur][r];
            float4 a   = a_b[cur][r];
            size_t idx = base + (size_t)(c * CH + r) * ROW4;

            f32x4 w;
            w.x = cf.x * aTE.x - cf.w * a.x;
            w.y = cf.x * aTE.y - cf.w * a.y;
            w.z = cf.x * aTE.z - cf.w * a.z;
            w.w = cf.x * aTE.w - cf.w * a.w;
            __builtin_nontemporal_store(w, &wt4[idx]);

            bx += cf.z * a.x - cf.y * aTE.x;
            by += cf.z * a.y - cf.y * aTE.y;
            bz += cf.z * a.z - cf.y * aTE.z;
            bw += cf.z * a.w - cf.y * aTE.w;

            float dot = aTE.x * a.x + aTE.y * a.y + aTE.z * a.z + aTE.w * a.w;
            float sq  = a.x * a.x + a.y * a.y + a.z * a.z + a.w * a.w;
            tr += 2.0f * cf.x * dot - cf.w * sq;
        }
    }

    // bTE partial sums -> device-scope float atomics (init_k wrote muvTE base)
    int v = v4 * 4;
    atomicAdd(&out[OFF_B + v + 0], bx);
    atomicAdd(&out[OFF_B + v + 1], by);
    atomicAdd(&out[OFF_B + v + 2], bz);
    atomicAdd(&out[OFF_B + v + 3], bw);

    // block-reduce trace partial: wave64 shuffle, then LDS across 4 waves
    for (int off = 32; off > 0; off >>= 1)
        tr += __shfl_down(tr, off);
    __shared__ float wsum[TPB / 64];
    if ((t & 63) == 0) wsum[t >> 6] = tr;
    __syncthreads();
    if (t == 0) {
        float s = wsum[0] + wsum[1] + wsum[2] + wsum[3];
        tr_partial[blockIdx.y * VBLK + blockIdx.x] = s;
    }
}

__global__ __launch_bounds__(TPB) void fin_k(
    const float* __restrict__ tr_partial,
    const float* __restrict__ varvbarTE,
    float* __restrict__ out)
{
    int t = threadIdx.x;
    float s = 0.f;
    for (int i = t; i < NPART; i += TPB) s += tr_partial[i];
    for (int off = 32; off > 0; off >>= 1)
        s += __shfl_down(s, off);
    __shared__ float wsum[TPB / 64];
    if ((t & 63) == 0) wsum[t >> 6] = s;
    __syncthreads();
    if (t == 0) {
        float tr = wsum[0] + wsum[1] + wsum[2] + wsum[3];
        out[OFF_SIG] = (varvbarTE[0] - tr) / (float)NV;
    }
}

extern "C" void kernel_launch(void* const* d_in, const int* in_sizes, int n_in,
                              void* d_out, int out_size, void* d_ws, size_t ws_size,
                              hipStream_t stream) {
    const float* muvTE       = (const float*)d_in[0];
    const float* varvhTE     = (const float*)d_in[1];
    const float* varh_diagTE = (const float*)d_in[2];
    const float* varh_diag   = (const float*)d_in[3];
    const float* muh         = (const float*)d_in[4];
    const float* varvh       = (const float*)d_in[5];
    const float* muhTE       = (const float*)d_in[6];
    const float* varvbarTE   = (const float*)d_in[7];
    float* out        = (float*)d_out;
    float* tr_partial = (float*)d_ws;   // NPART floats = 8 KB

    init_k<<<NV / TPB, TPB, 0, stream>>>(muvTE, varh_diagTE, muhTE, out);
    main_k<<<dim3(VBLK, HCH), TPB, 0, stream>>>(
        (const float4*)varvhTE, (const float4*)varvh,
        varh_diagTE, varh_diag, muh, muhTE, out, tr_partial);
    fin_k<<<1, TPB, 0, stream>>>(tr_partial, varvbarTE, out);
}

// Round 4
// 349.137 us; speedup vs baseline: 1.0307x; 1.0307x over previous
//
#include <hip/hip_runtime.h>

#define NV 8192
#define NH 4096
#define TPB 256
#define HPB 8                      // h rows per block: all rows' loads fit in regs
#define HCH (NH / HPB)             // 512 h-chunks (gridDim.y)
#define ROW4 (NV / 4)              // 2048 float4 per row
#define VBLK (ROW4 / TPB)          // 8 blocks in x
#define NPART (VBLK * HCH)         // 4096 trace partials (16 KB workspace)

typedef float f32x4 __attribute__((ext_vector_type(4)));  // native vec for nontemporal store

// output layout (flat float offsets, reference return order)
#define OFF_B   ((size_t)0)
#define OFF_WT  ((size_t)NV)
#define OFF_SIG ((size_t)NV + (size_t)NH * (size_t)NV)
#define OFF_MUH (OFF_SIG + 1)
#define OFF_VHD (OFF_MUH + NH)

__global__ __launch_bounds__(TPB) void init_k(
    const float* __restrict__ muvTE,
    const float* __restrict__ varh_diagTE,
    const float* __restrict__ muhTE,
    float* __restrict__ out)
{
    int i = blockIdx.x * TPB + threadIdx.x;     // grid covers NV
    if (i < NV) out[OFF_B + i] = muvTE[i];
    if (i < NH) {
        out[OFF_MUH + i] = muhTE[i];
        out[OFF_VHD + i] = varh_diagTE[i];
    }
}

// Structural anti-vmcnt(0) shape: ALL 16 loads issue before ANY store in
// program order (fence-pinned). A wave then has 16 KB of reads in flight,
// first compute waits on loads only, and the 8 nt-stores drain at kernel
// end overlapped with other blocks. __launch_bounds__(256,4): 128-VGPR
// budget for the 64 data VGPRs + addresses.
__global__ __launch_bounds__(TPB, 4) void main_k(
    const float4* __restrict__ varvhTE4,
    const float4* __restrict__ varvh4,
    const float* __restrict__ varh_diagTE,
    const float* __restrict__ varh_diag,
    const float* __restrict__ muh,
    const float* __restrict__ muhTE,
    float* __restrict__ out,
    float* __restrict__ tr_partial)
{
    __shared__ float4 coef_s[HPB];
    const int t  = threadIdx.x;
    const int h0 = blockIdx.y * HPB;

    // per-h coefficients: {inv, inv*muh, d*muh - inv*muhTE, d}
    if (t < HPB) {
        int h = h0 + t;
        float inv  = 1.0f / varh_diag[h];
        float vte  = varh_diagTE[h];
        float d    = inv * vte * inv;
        float m    = muh[h];
        coef_s[t] = make_float4(inv, inv * m, d * m - inv * muhTE[h], d);
    }
    __syncthreads();

    const int v4 = blockIdx.x * TPB + t;        // float4 column index
    f32x4* wt4 = (f32x4*)(out + OFF_WT);
    const size_t base = (size_t)h0 * ROW4 + (size_t)v4;

    // ---- phase 1: issue ALL loads (16 x dwordx4 = 64 data VGPRs) ----
    float4 aTE_r[HPB], a_r[HPB];
    #pragma unroll
    for (int r = 0; r < HPB; ++r) {
        size_t idx = base + (size_t)r * ROW4;
        aTE_r[r] = varvhTE4[idx];
        a_r[r]   = varvh4[idx];
    }
    // compiler memory fence: no store may be hoisted above, no load sunk below
    asm volatile("" ::: "memory");

    // ---- phase 2: compute + store (stores are the youngest vmem ops) ----
    float bx = 0.f, by = 0.f, bz = 0.f, bw = 0.f;
    float tr = 0.f;

    #pragma unroll
    for (int r = 0; r < HPB; ++r) {
        float4 cf  = coef_s[r];
        float4 aTE = aTE_r[r];
        float4 a   = a_r[r];
        size_t idx = base + (size_t)r * ROW4;

        f32x4 w;
        w.x = cf.x * aTE.x - cf.w * a.x;
        w.y = cf.x * aTE.y - cf.w * a.y;
        w.z = cf.x * aTE.z - cf.w * a.z;
        w.w = cf.x * aTE.w - cf.w * a.w;
        __builtin_nontemporal_store(w, &wt4[idx]);

        bx += cf.z * a.x - cf.y * aTE.x;
        by += cf.z * a.y - cf.y * aTE.y;
        bz += cf.z * a.z - cf.y * aTE.z;
        bw += cf.z * a.w - cf.y * aTE.w;

        float dot = aTE.x * a.x + aTE.y * a.y + aTE.z * a.z + aTE.w * a.w;
        float sq  = a.x * a.x + a.y * a.y + a.z * a.z + a.w * a.w;
        tr += 2.0f * cf.x * dot - cf.w * sq;
    }

    // bTE partial sums -> device-scope float atomics (init_k wrote muvTE base)
    int v = v4 * 4;
    atomicAdd(&out[OFF_B + v + 0], bx);
    atomicAdd(&out[OFF_B + v + 1], by);
    atomicAdd(&out[OFF_B + v + 2], bz);
    atomicAdd(&out[OFF_B + v + 3], bw);

    // block-reduce trace partial: wave64 shuffle, then LDS across 4 waves
    for (int off = 32; off > 0; off >>= 1)
        tr += __shfl_down(tr, off);
    __shared__ float wsum[TPB / 64];
    if ((t & 63) == 0) wsum[t >> 6] = tr;
    __syncthreads();
    if (t == 0) {
        float s = wsum[0] + wsum[1] + wsum[2] + wsum[3];
        tr_partial[blockIdx.y * VBLK + blockIdx.x] = s;
    }
}

__global__ __launch_bounds__(TPB) void fin_k(
    const float* __restrict__ tr_partial,
    const float* __restrict__ varvbarTE,
    float* __restrict__ out)
{
    int t = threadIdx.x;
    float s = 0.f;
    for (int i = t; i < NPART; i += TPB) s += tr_partial[i];
    for (int off = 32; off > 0; off >>= 1)
        s += __shfl_down(s, off);
    __shared__ float wsum[TPB / 64];
    if ((t & 63) == 0) wsum[t >> 6] = s;
    __syncthreads();
    if (t == 0) {
        float tr = wsum[0] + wsum[1] + wsum[2] + wsum[3];
        out[OFF_SIG] = (varvbarTE[0] - tr) / (float)NV;
    }
}

extern "C" void kernel_launch(void* const* d_in, const int* in_sizes, int n_in,
                              void* d_out, int out_size, void* d_ws, size_t ws_size,
                              hipStream_t stream) {
    const float* muvTE       = (const float*)d_in[0];
    const float* varvhTE     = (const float*)d_in[1];
    const float* varh_diagTE = (const float*)d_in[2];
    const float* varh_diag   = (const float*)d_in[3];
    const float* muh         = (const float*)d_in[4];
    const float* varvh       = (const float*)d_in[5];
    const float* muhTE       = (const float*)d_in[6];
    const float* varvbarTE   = (const float*)d_in[7];
    float* out        = (float*)d_out;
    float* tr_partial = (float*)d_ws;   // NPART floats = 16 KB

    init_k<<<NV / TPB, TPB, 0, stream>>>(muvTE, varh_diagTE, muhTE, out);
    main_k<<<dim3(VBLK, HCH), TPB, 0, stream>>>(
        (const float4*)varvhTE, (const float4*)varvh,
        varh_diagTE, varh_diag, muh, muhTE, out, tr_partial);
    fin_k<<<1, TPB, 0, stream>>>(tr_partial, varvbarTE, out);
}

// Round 5
// 345.380 us; speedup vs baseline: 1.0419x; 1.0109x over previous
//
#include <hip/hip_runtime.h>

#define NV 8192
#define NH 4096
#define TPB 256
#define HPB 8                      // h rows per block: 16 float4 loads per thread
#define HCH (NH / HPB)             // 512 h-chunks (gridDim.y)
#define ROW4 (NV / 4)              // 2048 float4 per row
#define VBLK (ROW4 / TPB)          // 8 blocks in x
#define NPART (VBLK * HCH)         // 4096 trace partials (16 KB workspace)

typedef float f32x4 __attribute__((ext_vector_type(4)));  // native vec for nontemporal store

// output layout (flat float offsets, reference return order)
#define OFF_B   ((size_t)0)
#define OFF_WT  ((size_t)NV)
#define OFF_SIG ((size_t)NV + (size_t)NH * (size_t)NV)
#define OFF_MUH (OFF_SIG + 1)
#define OFF_VHD (OFF_MUH + NH)

__global__ __launch_bounds__(TPB) void init_k(
    const float* __restrict__ muvTE,
    const float* __restrict__ varh_diagTE,
    const float* __restrict__ muhTE,
    float* __restrict__ out)
{
    int i = blockIdx.x * TPB + threadIdx.x;     // grid covers NV
    if (i < NV) out[OFF_B + i] = muvTE[i];
    if (i < NH) {
        out[OFF_MUH + i] = muhTE[i];
        out[OFF_VHD + i] = varh_diagTE[i];
    }
}

// MLP-forcing shape: 16 loads issue back-to-back (pinned by memory fence),
// results are LAUNDERED through empty asm so the compiler cannot hoist the
// compute to each load (which collapsed depth to ~2 in rounds 0-4). Waits
// become counted in-order vmcnt(14),vmcnt(12),... -> 16 KB in flight/wave.
__global__ __launch_bounds__(TPB, 4) void main_k(
    const float4* __restrict__ varvhTE4,
    const float4* __restrict__ varvh4,
    const float* __restrict__ varh_diagTE,
    const float* __restrict__ varh_diag,
    const float* __restrict__ muh,
    const float* __restrict__ muhTE,
    float* __restrict__ out,
    float* __restrict__ tr_partial)
{
    __shared__ float4 coef_s[HPB];
    const int t  = threadIdx.x;
    const int h0 = blockIdx.y * HPB;

    // per-h coefficients: {inv, inv*muh, d*muh - inv*muhTE, d}
    if (t < HPB) {
        int h = h0 + t;
        float inv  = 1.0f / varh_diag[h];
        float vte  = varh_diagTE[h];
        float d    = inv * vte * inv;
        float m    = muh[h];
        coef_s[t] = make_float4(inv, inv * m, d * m - inv * muhTE[h], d);
    }
    __syncthreads();

    const int v4 = blockIdx.x * TPB + t;        // float4 column index
    f32x4* wt4 = (f32x4*)(out + OFF_WT);
    const size_t base = (size_t)h0 * ROW4 + (size_t)v4;

    // ---- phase 1: issue ALL 16 loads (64 data VGPRs) ----
    float4 aTE_r[HPB], a_r[HPB];
    #pragma unroll
    for (int r = 0; r < HPB; ++r) {
        size_t idx = base + (size_t)r * ROW4;
        aTE_r[r] = varvhTE4[idx];
        a_r[r]   = varvh4[idx];
    }
    // loads may not sink below this point
    asm volatile("" ::: "memory");
    // launder every component: compute below consumes these defs, so it
    // cannot be hoisted above the load block; waits become counted vmcnt.
    #pragma unroll
    for (int r = 0; r < HPB; ++r) {
        asm volatile("" : "+v"(aTE_r[r].x), "+v"(aTE_r[r].y),
                          "+v"(aTE_r[r].z), "+v"(aTE_r[r].w));
        asm volatile("" : "+v"(a_r[r].x), "+v"(a_r[r].y),
                          "+v"(a_r[r].z), "+v"(a_r[r].w));
    }

    // ---- phase 2: compute + store ----
    float bx = 0.f, by = 0.f, bz = 0.f, bw = 0.f;
    float tr = 0.f;

    #pragma unroll
    for (int r = 0; r < HPB; ++r) {
        float4 cf  = coef_s[r];
        float4 aTE = aTE_r[r];
        float4 a   = a_r[r];
        size_t idx = base + (size_t)r * ROW4;

        f32x4 w;
        w.x = cf.x * aTE.x - cf.w * a.x;
        w.y = cf.x * aTE.y - cf.w * a.y;
        w.z = cf.x * aTE.z - cf.w * a.z;
        w.w = cf.x * aTE.w - cf.w * a.w;
        __builtin_nontemporal_store(w, &wt4[idx]);

        bx += cf.z * a.x - cf.y * aTE.x;
        by += cf.z * a.y - cf.y * aTE.y;
        bz += cf.z * a.z - cf.y * aTE.z;
        bw += cf.z * a.w - cf.y * aTE.w;

        float dot = aTE.x * a.x + aTE.y * a.y + aTE.z * a.z + aTE.w * a.w;
        float sq  = a.x * a.x + a.y * a.y + a.z * a.z + a.w * a.w;
        tr += 2.0f * cf.x * dot - cf.w * sq;
    }

    // bTE partial sums -> device-scope float atomics (init_k wrote muvTE base)
    int v = v4 * 4;
    atomicAdd(&out[OFF_B + v + 0], bx);
    atomicAdd(&out[OFF_B + v + 1], by);
    atomicAdd(&out[OFF_B + v + 2], bz);
    atomicAdd(&out[OFF_B + v + 3], bw);

    // block-reduce trace partial: wave64 shuffle, then LDS across 4 waves
    for (int off = 32; off > 0; off >>= 1)
        tr += __shfl_down(tr, off);
    __shared__ float wsum[TPB / 64];
    if ((t & 63) == 0) wsum[t >> 6] = tr;
    __syncthreads();
    if (t == 0) {
        float s = wsum[0] + wsum[1] + wsum[2] + wsum[3];
        tr_partial[blockIdx.y * VBLK + blockIdx.x] = s;
    }
}

__global__ __launch_bounds__(TPB) void fin_k(
    const float* __restrict__ tr_partial,
    const float* __restrict__ varvbarTE,
    float* __restrict__ out)
{
    int t = threadIdx.x;
    float s = 0.f;
    for (int i = t; i < NPART; i += TPB) s += tr_partial[i];
    for (int off = 32; off > 0; off >>= 1)
        s += __shfl_down(s, off);
    __shared__ float wsum[TPB / 64];
    if ((t & 63) == 0) wsum[t >> 6] = s;
    __syncthreads();
    if (t == 0) {
        float tr = wsum[0] + wsum[1] + wsum[2] + wsum[3];
        out[OFF_SIG] = (varvbarTE[0] - tr) / (float)NV;
    }
}

extern "C" void kernel_launch(void* const* d_in, const int* in_sizes, int n_in,
                              void* d_out, int out_size, void* d_ws, size_t ws_size,
                              hipStream_t stream) {
    const float* muvTE       = (const float*)d_in[0];
    const float* varvhTE     = (const float*)d_in[1];
    const float* varh_diagTE = (const float*)d_in[2];
    const float* varh_diag   = (const float*)d_in[3];
    const float* muh         = (const float*)d_in[4];
    const float* varvh       = (const float*)d_in[5];
    const float* muhTE       = (const float*)d_in[6];
    const float* varvbarTE   = (const float*)d_in[7];
    float* out        = (float*)d_out;
    float* tr_partial = (float*)d_ws;   // NPART floats = 16 KB

    init_k<<<NV / TPB, TPB, 0, stream>>>(muvTE, varh_diagTE, muhTE, out);
    main_k<<<dim3(VBLK, HCH), TPB, 0, stream>>>(
        (const float4*)varvhTE, (const float4*)varvh,
        varh_diagTE, varh_diag, muh, muhTE, out, tr_partial);
    fin_k<<<1, TPB, 0, stream>>>(tr_partial, varvbarTE, out);
}